// Round 11
// baseline (197.362 us; speedup 1.0000x reference)
//
#include <hip/hip_runtime.h>
#include <hip/hip_bf16.h>
#include <math.h>

// B=8, H=W=128, CH=64, OC=64, NCA_C=128, K=3, dils {1,2,4,8}, HID=64
// out: y [8,128,128,64] fp32 (8388608) then c2 [8,64] fp32 (512)
//
// Depthwise conv folded into GEMM1 over 33 positions (center-merged), fp8-e4m3
// (U scaled x256). Round-11: MX K=128 MFMA (mfma_scale_f32_16x16x128_f8f6f4,
// identity scales) packs TWO positions per instruction -> MFMA pipe demand
// 17.3 -> 7.9 us/SIMD, half the instructions/iterations. 17 pairs (1 dummy).
//  - xpad: plain 64-B channel order; lane reads 32 B = its oct's (pos,ch-half)
//    per the A mapping k=(lane>>4)*32+j (oct>>1 = pos-in-pair, oct&1 = ch-half).
//  - U: pre-packed per pair in B-frag order [pair][nt][lane][32B].
//  - Ping-pong A/B register buffers (copy-free), NO LDS/barriers in K-loop.
//  - ONE prep kernel (c2 recomputed in-block: tiny matvec), tables global.
// b = blk&7 -> XCD-local L2.

typedef float f32x4 __attribute__((ext_vector_type(4)));
typedef short s16x8 __attribute__((ext_vector_type(8)));
typedef int   v8i   __attribute__((ext_vector_type(8)));

static __device__ __forceinline__ unsigned short f2bf(float f) {
    __hip_bfloat16 h = __float2bfloat16(f);
    unsigned short u; __builtin_memcpy(&u, &h, 2); return u;
}
static __device__ __forceinline__ unsigned pk4fp8(float f0, float f1, float f2, float f3) {
    int v = 0;
    v = __builtin_amdgcn_cvt_pk_fp8_f32(f0, f1, v, false);
    v = __builtin_amdgcn_cvt_pk_fp8_f32(f2, f3, v, true);
    return (unsigned)v;
}

// xpad (fp8): [b][yy(144)][xx(144)][64 B plain ch order]
#define XROWB  9216
#define XBATCH 1327104
#define USCALE 256.0f

// position tables (order: rows dy=-8,-4,-2,-1; merged center; dy=0 +-1+-2+-4+-8; rows +1,+2,+4,+8)
__device__ __constant__ int DIc[33] = {3,3,3, 2,2,2, 1,1,1, 0,0,0, -1, 0,0, 1,1, 2,2, 3,3,
                                       0,0,0, 1,1,1, 2,2,2, 3,3,3};
__device__ __constant__ int TTc[33] = {0,1,2, 0,1,2, 0,1,2, 0,1,2, 4, 3,5, 3,5, 3,5, 3,5,
                                       6,7,8, 6,7,8, 6,7,8, 6,7,8};

// ---- c2 recompute helper (block-local; removes inter-kernel dependency) ----
static __device__ void c2_block(int b, int tid,
    const float* __restrict__ c,  const float* __restrict__ Wv,
    const float* __restrict__ bv, const float* __restrict__ Wo,
    const float* __restrict__ bo, const float* __restrict__ lng,
    const float* __restrict__ lnb, float* sc2)
{
    __shared__ float vsh[64], tsh[64];
    if (tid < 64) sc2[tid] = c[b*64 + tid];
    __syncthreads();
    if (tid < 64) {
        float v = bv[tid];
        for (int i = 0; i < 64; ++i) v += sc2[i]*Wv[i*64 + tid];
        vsh[tid] = v;
    }
    __syncthreads();
    if (tid < 64) {
        float t = bo[tid] + sc2[tid];
        for (int i = 0; i < 64; ++i) t += vsh[i]*Wo[i*64 + tid];
        tsh[tid] = t;
    }
    __syncthreads();
    if (tid < 64) {
        float m = 0.f;
        for (int i = 0; i < 64; ++i) m += tsh[i];
        m *= (1.f/64.f);
        float vv = 0.f;
        for (int i = 0; i < 64; ++i) { float d = tsh[i] - m; vv += d*d; }
        vv *= (1.f/64.f);
        float a = (tsh[tid] - m) / sqrtf(vv + 1e-5f) * lng[tid] + lnb[tid];
        sc2[tid] = sc2[tid] + a;     // own-element RMW, single wave -> no barrier
    }
    __syncthreads();
}

// ---------------- prep: EVERYTHING in one launch -----------------------------
// [0,512) convert | [512,648) pad | [648,665) U pairs | [665,667) W2s |
// [667,739) V | [739,747) hc2g+outc2 | [747,779) CyGe | [779,811) CxG
__global__ void prep(const float* __restrict__ x,  const float* __restrict__ c,
                     const float* __restrict__ Wv, const float* __restrict__ bv,
                     const float* __restrict__ Wo, const float* __restrict__ bo,
                     const float* __restrict__ lng,const float* __restrict__ lnb,
                     const float* __restrict__ pk, const float* __restrict__ W1,
                     const float* __restrict__ W2, const float* __restrict__ b1,
                     unsigned char* __restrict__ xp, unsigned char* __restrict__ Uf,
                     unsigned short* __restrict__ W2s, float* __restrict__ V,
                     float* __restrict__ hc2g, float* __restrict__ CyGe,
                     float* __restrict__ CxG, float* __restrict__ outc2)
{
    const int blk = blockIdx.x, tid = threadIdx.x;
    __shared__ float c2s[64];
    if (blk < 512) {
        // x -> fp8, plain channel order
        int i = blk*256 + tid;
        int xc = i & 127, y = (i >> 7) & 127, b = i >> 14;
        const float* src = x + (size_t)i*64;
        unsigned P[16];
        #pragma unroll
        for (int k = 0; k < 16; ++k) {
            float4 f = *(const float4*)(src + k*4);
            P[k] = pk4fp8(f.x, f.y, f.z, f.w);
        }
        unsigned char* d = xp + (size_t)b*XBATCH + (size_t)(y+8)*XROWB + (size_t)(xc+8)*64;
        *(uint4*)(d +  0) = make_uint4(P[0],  P[1],  P[2],  P[3]);
        *(uint4*)(d + 16) = make_uint4(P[4],  P[5],  P[6],  P[7]);
        *(uint4*)(d + 32) = make_uint4(P[8],  P[9],  P[10], P[11]);
        *(uint4*)(d + 48) = make_uint4(P[12], P[13], P[14], P[15]);
    } else if (blk < 648) {
        int idx = (blk - 512)*256 + tid;     // [0,34816) pad px
        int b = idx / 4352, r = idx - b*4352;
        int yy, xx;
        if (r < 2304) { int ry = r / 144; xx = r - ry*144; yy = (ry < 8) ? ry : 128 + ry; }
        else { int r2 = r - 2304; yy = 8 + (r2 >> 4); int xi = r2 & 15; xx = (xi < 8) ? xi : 128 + xi; }
        unsigned char* d = xp + (size_t)b*XBATCH + (size_t)yy*XROWB + (size_t)xx*64;
        uint4 z = make_uint4(0,0,0,0);
        *(uint4*)(d) = z; *(uint4*)(d+16) = z; *(uint4*)(d+32) = z; *(uint4*)(d+48) = z;
    } else if (blk < 665) {
        // U MX pairs: entry idx=(pair*4+nt)*64+lane, 32 B each; pos = pair*2+(oct>>1)
        int idx = (blk - 648)*256 + tid;     // [0, 4352) = 17*4*64
        int lane = idx & 63, nt = (idx >> 6) & 3, pair = idx >> 8;
        int n   = nt*16 + (lane & 15);
        int oct = lane >> 4;
        int pos = pair*2 + (oct >> 1);
        int chh = (oct & 1)*32;
        unsigned Pw[8];
        if (pos > 32) {
            #pragma unroll
            for (int q = 0; q < 8; ++q) Pw[q] = 0u;
        } else {
            int di = DIc[pos], t = TTc[pos];
            float vv[32];
            #pragma unroll
            for (int j = 0; j < 32; ++j) {
                int ch = chh + j;
                float v;
                if (di < 0) {                // merged center: identity + 4 dil centers
                    v = W1[ch*64 + n];
                    for (int dd = 0; dd < 4; ++dd)
                        v += pk[(dd*128 + ch)*9 + 4] * W1[((1+dd)*128 + ch)*64 + n];
                } else {
                    v = pk[(di*128 + ch)*9 + t] * W1[((1+di)*128 + ch)*64 + n];
                }
                vv[j] = v * USCALE;
            }
            #pragma unroll
            for (int q = 0; q < 8; ++q)
                Pw[q] = pk4fp8(vv[q*4], vv[q*4+1], vv[q*4+2], vv[q*4+3]);
        }
        uint4* d = (uint4*)(Uf + (size_t)idx*32);
        d[0] = make_uint4(Pw[0], Pw[1], Pw[2], Pw[3]);
        d[1] = make_uint4(Pw[4], Pw[5], Pw[6], Pw[7]);
    } else if (blk < 667) {
        int idx = (blk - 665)*256 + tid;     // [0,512)
        int lane = idx & 63, nt = (idx >> 6) & 3, kc2 = (idx >> 8) & 1;
        int n  = nt*16 + (lane & 15);
        int k0 = kc2*32 + (lane >> 4)*8;
        unsigned short e[8];
        #pragma unroll
        for (int j = 0; j < 8; ++j) e[j] = f2bf(W2[(k0+j)*64 + n]);
        uint4 o;
        o.x = (unsigned)e[0] | ((unsigned)e[1] << 16);
        o.y = (unsigned)e[2] | ((unsigned)e[3] << 16);
        o.z = (unsigned)e[4] | ((unsigned)e[5] << 16);
        o.w = (unsigned)e[6] | ((unsigned)e[7] << 16);
        *(uint4*)(W2s + (size_t)idx*8) = o;
    } else if (blk < 739) {
        // V[b][p][n]: const-channel tap contributions (9 blocks per b)
        int blkl = blk - 667;
        int b = blkl / 9;
        c2_block(b, tid, c, Wv, bv, Wo, bo, lng, lnb, c2s);
        int idx = (blkl % 9)*256 + tid;      // [0,2304)
        int p = idx >> 6, n = idx & 63;
        int di = p/9, t = p%9;
        float s = 0.f;
        for (int j = 0; j < 64; ++j)
            s += c2s[j] * pk[(di*128 + 64 + j)*9 + t] * W1[((1+di)*128 + 64 + j)*64 + n];
        V[((size_t)b*36 + p)*64 + n] = s;
    } else if (blk < 747) {
        // hc2g[b][n] + outc2
        int b = blk - 739;
        c2_block(b, tid, c, Wv, bv, Wo, bo, lng, lnb, c2s);
        if (tid < 64) {
            int n = tid;
            float s = b1[n];
            for (int j = 0; j < 64; ++j) {
                float wsum = W1[(64 + j)*64 + n];
                for (int di = 0; di < 4; ++di) {
                    float ks = 0.f;
                    for (int t = 0; t < 9; ++t) ks += pk[(di*128 + 64 + j)*9 + t];
                    wsum += ks * W1[((1+di)*128 + 64 + j)*64 + n];
                }
                s += c2s[j] * wsum;
            }
            hc2g[b*64 + n] = s;
            outc2[b*64 + n] = c2s[n];
        }
    } else if (blk < 779) {
        // CyGe[b][yi(16)][n]: y-edge correction, yi<8 -> y=yi else y=112+yi
        int blkl = blk - 747;
        int b = blkl / 4;
        c2_block(b, tid, c, Wv, bv, Wo, bo, lng, lnb, c2s);
        int idx = (blkl % 4)*256 + tid;      // [0,1024)
        int yi = idx >> 6, n = idx & 63;
        int y = (yi < 8) ? yi : 112 + yi;
        float s = 0.f;
        for (int di = 0; di < 4; ++di) {
            int d = 1 << di;
            int dyo = (y < d) ? 0 : ((y >= 128 - d) ? 2 : -1);
            if (dyo >= 0) {
                for (int j = 0; j < 64; ++j) {
                    float pks = pk[(di*128 + 64 + j)*9 + dyo*3 + 0]
                              + pk[(di*128 + 64 + j)*9 + dyo*3 + 1]
                              + pk[(di*128 + 64 + j)*9 + dyo*3 + 2];
                    s += c2s[j] * pks * W1[((1+di)*128 + 64 + j)*64 + n];
                }
            }
        }
        CyGe[((b << 4) + yi)*64 + n] = s;
    } else {
        // CxG[b][xi(16)][n]: x-edge correction, xi<8 -> x=xi else x=112+xi
        int blkl = blk - 779;
        int b = blkl / 4;
        c2_block(b, tid, c, Wv, bv, Wo, bo, lng, lnb, c2s);
        int idx = (blkl % 4)*256 + tid;      // [0,1024)
        int xi = idx >> 6, n = idx & 63;
        int xx = (xi < 8) ? xi : 112 + xi;
        float s = 0.f;
        for (int di = 0; di < 4; ++di) {
            int d = 1 << di;
            int dxo = (xx < d) ? 0 : ((xx >= 128 - d) ? 2 : -1);
            if (dxo >= 0) {
                for (int j = 0; j < 64; ++j) {
                    float pks = pk[(di*128 + 64 + j)*9 + 0*3 + dxo]
                              + pk[(di*128 + 64 + j)*9 + 1*3 + dxo]
                              + pk[(di*128 + 64 + j)*9 + 2*3 + dxo];
                    s += c2s[j] * pks * W1[((1+di)*128 + 64 + j)*64 + n];
                }
            }
        }
        CxG[((b << 4) + xi)*64 + n] = s;
    }
}

// ---------------- main fused kernel -----------------------------------------
#define HID_S 72

__global__ __launch_bounds__(256) void nca_main(
    const unsigned char* __restrict__ xp,
    const unsigned char* __restrict__ U,
    const unsigned short* __restrict__ W2s,
    const float* __restrict__ V,
    const float* __restrict__ hc2g,
    const float* __restrict__ CyGe,
    const float* __restrict__ CxG,
    const float* __restrict__ b2,
    float* __restrict__ out)
{
    __shared__ unsigned short hid[256*HID_S];  // 36,864 B (only LDS)

    const int tid = threadIdx.x;
    const int blk = blockIdx.x;
    const int b  = blk & 7;                    // XCD-local batch
    const int y0 = (blk >> 3) * 2;

    const int lane = tid & 63;
    const int w    = tid >> 6;          // wave: row = y0+(w>>1), x-half = (w&1)*64
    const int y    = y0 + (w >> 1);
    const int xw   = (w & 1) * 64;
    const int ln15 = lane & 15;
    const int oct  = lane >> 4;
    const int hi   = oct >> 1;          // pos-in-pair selector

    const unsigned char* abase = xp + (size_t)b*XBATCH + (size_t)(y + 8)*XROWB
                               + (size_t)(xw + ln15 + 8)*64 + (oct & 1)*32;
    const unsigned char* ubase = U + (size_t)lane*32;

    f32x4 acc[4][4];
    #pragma unroll
    for (int mt = 0; mt < 4; ++mt)
        #pragma unroll
        for (int nt = 0; nt < 4; ++nt) {
            acc[mt][nt][0] = 0.f; acc[mt][nt][1] = 0.f;
            acc[mt][nt][2] = 0.f; acc[mt][nt][3] = 0.f;
        }

    // byte offsets (px stride 64 B); index 33 = dummy (U zero)
    static constexpr int OFF[34] = {
        (-8*144-8)*64, (-8*144)*64, (-8*144+8)*64,
        (-4*144-4)*64, (-4*144)*64, (-4*144+4)*64,
        (-2*144-2)*64, (-2*144)*64, (-2*144+2)*64,
        (-1*144-1)*64, (-1*144)*64, (-1*144+1)*64,
        0,
        -64, 64, -128, 128, -256, 256, -512, 512,
        ( 1*144-1)*64, ( 1*144)*64, ( 1*144+1)*64,
        ( 2*144-2)*64, ( 2*144)*64, ( 2*144+2)*64,
        ( 4*144-4)*64, ( 4*144)*64, ( 4*144+4)*64,
        ( 8*144-8)*64, ( 8*144)*64, ( 8*144+8)*64,
        0
    };

    v8i A0[4], A1[4], B0[4], B1[4];
    auto loadAB = [&](v8i* A, v8i* B, int P) {
        int off = hi ? OFF[2*P + 1] : OFF[2*P];
        const unsigned char* rp = abase + off;
        #pragma unroll
        for (int mt = 0; mt < 4; ++mt) A[mt] = *(const v8i*)(rp + mt*1024);
        const unsigned char* up = ubase + (size_t)P*8192;
        #pragma unroll
        for (int nt = 0; nt < 4; ++nt) B[nt] = *(const v8i*)(up + nt*2048);
    };
    auto mfblk = [&](v8i* A, v8i* B) {
        #pragma unroll
        for (int nt = 0; nt < 4; ++nt)
            #pragma unroll
            for (int mt = 0; mt < 4; ++mt)
                acc[mt][nt] = __builtin_amdgcn_mfma_scale_f32_16x16x128_f8f6f4(
                    A[mt], B[nt], acc[mt][nt], 0, 0, 0, 127, 0, 127);
    };

    loadAB(A0, B0, 0);
    loadAB(A1, B1, 1);
    #pragma unroll 1
    for (int i = 0; i < 8; ++i) {
        mfblk(A0, B0);
        int pa = 2*i + 2;                       // <= 16
        loadAB(A0, B0, pa);
        mfblk(A1, B1);
        int pb = (2*i + 3 <= 16) ? (2*i + 3) : 16;
        loadAB(A1, B1, pb);
    }
    mfblk(A0, B0);                              // pair 16 (pos 32 + dummy)

    // ---- epilogue 1: acc/256 + hc2 - Cy - Cx (+corner V), GELU, hid ----
    const bool yedge = (y < 8) || (y >= 120);
    const int  yi    = (y < 8) ? y : (y - 112);
    float hcv[4];
    #pragma unroll
    for (int nt = 0; nt < 4; ++nt) {
        const int n = nt*16 + ln15;
        hcv[nt] = hc2g[b*64 + n] - (yedge ? CyGe[((b << 4) + yi)*64 + n] : 0.f);
    }
    #pragma unroll
    for (int mt = 0; mt < 4; ++mt) {
        #pragma unroll
        for (int nt = 0; nt < 4; ++nt) {
            const int n = nt*16 + ln15;
            #pragma unroll
            for (int r = 0; r < 4; ++r) {
                int m = mt*16 + oct*4 + r;       // wrong? C row = (lane>>4)*4+reg
                int x = xw + m;
                float h = acc[mt][nt][r]*(1.0f/USCALE) + hcv[nt];
                if (x < 8 || x >= 120) {
                    int xi = (x < 8) ? x : (x - 112);
                    h -= CxG[((b << 4) + xi)*64 + n];
                    if (yedge) {                 // corner double-subtract fix
                        #pragma unroll
                        for (int di = 0; di < 4; ++di) {
                            int d = 1 << di;
                            int dyo = (y < d) ? 0 : ((y >= 128 - d) ? 2 : -1);
                            int dxo = (x < d) ? 0 : ((x >= 128 - d) ? 2 : -1);
                            if (dyo >= 0 && dxo >= 0)
                                h += V[((size_t)b*36 + di*9 + dyo*3 + dxo)*64 + n];
                        }
                    }
                }
                float u = 0.7978845608028654f * (h + 0.044715f*h*h*h);
                float g = h / (1.f + __expf(-2.f*u));
                hid[(w*64 + m)*HID_S + n] = f2bf(g);
            }
        }
    }
    // each wave reads back only its own 64 hid rows -> no barrier needed

    // ---- GEMM2: y = hid @ W2 + b2 (bf16 16x16x32) ----
    f32x4 acc2[4][4];
    #pragma unroll
    for (int mt = 0; mt < 4; ++mt)
        #pragma unroll
        for (int nt = 0; nt < 4; ++nt) {
            acc2[mt][nt][0] = 0.f; acc2[mt][nt][1] = 0.f;
            acc2[mt][nt][2] = 0.f; acc2[mt][nt][3] = 0.f;
        }
    #pragma unroll
    for (int kc2 = 0; kc2 < 2; ++kc2) {
        s16x8 a2[4];
        #pragma unroll
        for (int mt = 0; mt < 4; ++mt)
            a2[mt] = *(const s16x8*)&hid[(w*64 + mt*16 + ln15)*HID_S + kc2*32 + oct*8];
        #pragma unroll
        for (int nt = 0; nt < 4; ++nt) {
            s16x8 bf = *(const s16x8*)(W2s + ((size_t)(kc2*4 + nt)*64 + lane)*8);
            #pragma unroll
            for (int mt = 0; mt < 4; ++mt)
                acc2[mt][nt] = __builtin_amdgcn_mfma_f32_16x16x32_bf16(a2[mt], bf, acc2[mt][nt], 0, 0, 0);
        }
    }

    float* ob = out + ((size_t)(b*128 + y))*128*64;
    #pragma unroll
    for (int nt = 0; nt < 4; ++nt) {
        const float b2v = b2[nt*16 + ln15];
        #pragma unroll
        for (int mt = 0; mt < 4; ++mt) {
            #pragma unroll
            for (int r = 0; r < 4; ++r) {
                int x = xw + mt*16 + oct*4 + r;
                ob[(size_t)x*64 + nt*16 + ln15] = acc2[mt][nt][r] + b2v;
            }
        }
    }
}

// ---------------- launch ----------------------------------------------------
extern "C" void kernel_launch(void* const* d_in, const int* in_sizes, int n_in,
                              void* d_out, int out_size, void* d_ws, size_t ws_size,
                              hipStream_t stream) {
    const float* x   = (const float*)d_in[0];
    const float* c   = (const float*)d_in[1];
    // d_in[2..5] = Wq,bq,Wk,bk : unused (softmax weights sum to 1 -> pool == v)
    const float* Wv  = (const float*)d_in[6];
    const float* bv  = (const float*)d_in[7];
    const float* Wo  = (const float*)d_in[8];
    const float* bo  = (const float*)d_in[9];
    const float* lng = (const float*)d_in[10];
    const float* lnb = (const float*)d_in[11];
    const float* pk  = (const float*)d_in[12];
    const float* W1  = (const float*)d_in[13];
    const float* b1  = (const float*)d_in[14];
    const float* W2  = (const float*)d_in[15];
    const float* b2  = (const float*)d_in[16];
    float* out = (float*)d_out;

    char* w = (char*)d_ws;
    unsigned char*  xpb  = (unsigned char*)(w);                  // 10,616,832 B
    unsigned char*  Uf   = (unsigned char*)(w + 10616832);       //    139,264 B
    unsigned short* W2s  = (unsigned short*)(w + 10756096);      //      8,192 B
    float*          V    = (float*)         (w + 10764288);      //     73,728 B
    float*          hc2g = (float*)         (w + 10838016);      //      2,048 B
    float*          CyGe = (float*)         (w + 10840064);      //     32,768 B
    float*          CxG  = (float*)         (w + 10872832);      //     32,768 B (end 10,905,600)

    prep<<<811, 256, 0, stream>>>(x, c, Wv, bv, Wo, bo, lng, lnb, pk, W1, W2, b1,
                                  xpb, Uf, W2s, V, hc2g, CyGe, CxG, out + 8388608);
    nca_main<<<512, 256, 0, stream>>>(xpb, Uf, W2s, V, hc2g, CyGe, CxG, b2, out);
}